// Round 1
// baseline (343.239 us; speedup 1.0000x reference)
//
#include <hip/hip_runtime.h>

#define H 1024
#define W 2048
#define WP1f 2049.0f   // W + 1
#define TB 32

// ---------------------------------------------------------------------------
// Bilinear 1D sample of a W-length row with zero border padding (pad=1),
// x already clamped to [0, W+1]. Matches reference warp1d semantics:
// padded index i in [0,W+1], p[0]=p[W+1]=0, p[i]=row[i-1].
__device__ __forceinline__ float sample_row(const float* __restrict__ row, float x) {
    float x0 = floorf(x);
    float x1 = fminf(x0 + 1.0f, WP1f);
    int i0 = (int)x0;
    int i1 = (int)x1;
    float wl = x1 - x;
    float wr = x - x0;
    float pl = (i0 >= 1 && i0 <= W) ? row[i0 - 1] : 0.0f;
    float pr = (i1 >= 1 && i1 <= W) ? row[i1 - 1] : 0.0f;
    return wl * pl + wr * pr;
}

__device__ __forceinline__ float clampx(float x) {
    return fminf(fmaxf(x, 0.0f), WP1f);
}

// ---------------------------------------------------------------------------
// Kernel A: per-row warps + SAD + LR-consistency sums + gray maps.
// acc[0]=sadL, acc[1]=sadR, acc[2]=lr1 (|r2l - dl|), acc[3]=lr2 (|l2r - dr|)
__global__ __launch_bounds__(256)
void row_kernel(const float* __restrict__ dispL, const float* __restrict__ dispR,
                const float* __restrict__ left, const float* __restrict__ right,
                float* __restrict__ glm, float* __restrict__ grm,
                float* __restrict__ gelm, float* __restrict__ germ,
                double* __restrict__ acc) {
    __shared__ float sl[3 * W];   // left row, 3 channels (gather target of est_right)
    __shared__ float sr[3 * W];   // right row, 3 channels (gather target of est_left)
    __shared__ float sacc[4];
    const int h = blockIdx.x;
    const int tid = threadIdx.x;
    if (tid < 4) sacc[tid] = 0.0f;

    for (int c = 0; c < 3; ++c) {
        const float* Lrow = left + ((size_t)c * H + h) * W;
        const float* Rrow = right + ((size_t)c * H + h) * W;
        for (int j = tid; j < W; j += 256) {
            sl[c * W + j] = Lrow[j];
            sr[c * W + j] = Rrow[j];
        }
    }
    __syncthreads();

    const float* dlrow = dispL + (size_t)h * W;
    const float* drrow = dispR + (size_t)h * W;
    float a_sadL = 0.f, a_sadR = 0.f, a_lr1 = 0.f, a_lr2 = 0.f;

    for (int j = tid; j < W; j += 256) {
        float dl = dlrow[j];
        float dr = drrow[j];
        float xr = clampx((float)(j + 1) + dr);  // sample position into LEFT row
        float xl = clampx((float)(j + 1) - dl);  // sample position into RIGHT row

        float er0 = sample_row(sl,         xr);
        float er1 = sample_row(sl + W,     xr);
        float er2 = sample_row(sl + 2 * W, xr);
        float el0 = sample_row(sr,         xl);
        float el1 = sample_row(sr + W,     xl);
        float el2 = sample_row(sr + 2 * W, xl);

        float l0 = sl[j], l1 = sl[W + j], l2 = sl[2 * W + j];
        float r0 = sr[j], r1 = sr[W + j], r2 = sr[2 * W + j];

        a_sadL += fabsf(l0 - el0) + fabsf(l1 - el1) + fabsf(l2 - el2);
        a_sadR += fabsf(r0 - er0) + fabsf(r1 - er1) + fabsf(r2 - er2);

        size_t p = (size_t)h * W + j;
        glm[p]  = (l0 + l1 + l2) * (1.0f / 3.0f);
        grm[p]  = (r0 + r1 + r2) * (1.0f / 3.0f);
        gelm[p] = (el0 + el1 + el2) * (1.0f / 3.0f);
        germ[p] = (er0 + er1 + er2) * (1.0f / 3.0f);

        // LR consistency: l2r = warp1d(disp_left, disp_right) -> sample dl row at xr
        //                 r2l = warp1d(disp_right, -disp_left) -> sample dr row at xl
        float l2rv = sample_row(dlrow, xr);
        float r2lv = sample_row(drrow, xl);
        a_lr1 += fabsf(r2lv - dl);
        a_lr2 += fabsf(l2rv - dr);
    }

    // wave reduce (64 lanes) then shared, then one double atomic per block
    for (int off = 32; off > 0; off >>= 1) {
        a_sadL += __shfl_down(a_sadL, off, 64);
        a_sadR += __shfl_down(a_sadR, off, 64);
        a_lr1  += __shfl_down(a_lr1,  off, 64);
        a_lr2  += __shfl_down(a_lr2,  off, 64);
    }
    if ((tid & 63) == 0) {
        atomicAdd(&sacc[0], a_sadL);
        atomicAdd(&sacc[1], a_sadR);
        atomicAdd(&sacc[2], a_lr1);
        atomicAdd(&sacc[3], a_lr2);
    }
    __syncthreads();
    if (tid == 0) {
        atomicAdd(&acc[0], (double)sacc[0]);
        atomicAdd(&acc[1], (double)sacc[1]);
        atomicAdd(&acc[2], (double)sacc[2]);
        atomicAdd(&acc[3], (double)sacc[3]);
    }
}

// ---------------------------------------------------------------------------
// Kernel B: SSIM with the reference's nested pooling, both windows (3,5),
// z = pair (0: gl/gel, 1: gr/ger). acc[4+2*pair+wi] += sum of clipped vals.
__global__ __launch_bounds__(256)
void ssim_kernel(const float* __restrict__ glm, const float* __restrict__ gelm,
                 const float* __restrict__ grm, const float* __restrict__ germ,
                 double* __restrict__ acc) {
    __shared__ float xt[40][40];
    __shared__ float yt[40][40];
    __shared__ float mux[36][36];
    __shared__ float muy[36][36];
    __shared__ float ssum;

    const int r0 = blockIdx.y * TB;
    const int c0 = blockIdx.x * TB;
    const int pair = blockIdx.z;
    const float* xg = pair ? grm : glm;
    const float* yg = pair ? germ : gelm;
    const int tid = threadIdx.x;
    if (tid == 0) ssum = 0.0f;

    for (int idx = tid; idx < 40 * 40; idx += 256) {
        int r = idx / 40, c = idx % 40;
        int gi = r0 + r, gj = c0 + c;
        float xv = 0.f, yv = 0.f;
        if (gi < H && gj < W) {
            size_t p = (size_t)gi * W + gj;
            xv = xg[p]; yv = yg[p];
        }
        xt[r][c] = xv;
        yt[r][c] = yv;
    }
    __syncthreads();

    const float C1 = 1e-4f, C2 = 9e-4f;

    for (int wi = 0; wi < 2; ++wi) {
        const int w = wi ? 5 : 3;
        const int cc = (w - 1) / 2;
        const int ME = TB + w - 1;            // mu extent: 34 (w=3) / 36 (w=5)
        const float inv = 1.0f / (float)(w * w);

        for (int idx = tid; idx < ME * ME; idx += 256) {
            int p = idx / ME, q = idx % ME;
            float sx = 0.f, sy = 0.f;
            for (int u = 0; u < w; ++u)
                for (int v = 0; v < w; ++v) {
                    sx += xt[p + u][q + v];
                    sy += yt[p + u][q + v];
                }
            mux[p][q] = sx * inv;
            muy[p][q] = sy * inv;
        }
        __syncthreads();

        float vsum = 0.f;
        const int HB = H - 2 * (w - 1), WB = W - 2 * (w - 1);
        for (int idx = tid; idx < TB * TB; idx += 256) {
            int li = idx / TB, lj = idx % TB;
            int gi = r0 + li, gj = c0 + lj;
            if (gi < HB && gj < WB) {
                float sxx = 0.f, syy = 0.f, sxy = 0.f;
                for (int a = 0; a < w; ++a)
                    for (int b = 0; b < w; ++b) {
                        float dx = xt[li + cc + a][lj + cc + b] - mux[li + a][lj + b];
                        float dy = yt[li + cc + a][lj + cc + b] - muy[li + a][lj + b];
                        sxx += dx * dx;
                        syy += dy * dy;
                        sxy += dx * dy;
                    }
                sxx *= inv; syy *= inv; sxy *= inv;
                float mx = mux[li + cc][lj + cc];
                float my = muy[li + cc][lj + cc];
                float n = (2.f * mx * my + C1) * (2.f * sxy + C2);
                float d = (mx * mx + my * my + C1) * (sxx + syy + C2);
                float val = fminf(fmaxf(1.f - n / d, 0.f), 2.f);
                vsum += val;
            }
        }

        for (int off = 32; off > 0; off >>= 1) vsum += __shfl_down(vsum, off, 64);
        if ((tid & 63) == 0) atomicAdd(&ssum, vsum);
        __syncthreads();
        if (tid == 0) {
            atomicAdd(&acc[4 + 2 * pair + wi], (double)ssum);
            ssum = 0.0f;
        }
        // next iteration's __syncthreads (after mu compute) orders the reset
    }
}

// ---------------------------------------------------------------------------
// Kernel C: disparity smoothness. z=0: (disp_left, gl)->acc[8], z=1: ->acc[9]
__global__ __launch_bounds__(256)
void smooth_kernel(const float* __restrict__ dispL, const float* __restrict__ dispR,
                   const float* __restrict__ glm, const float* __restrict__ grm,
                   double* __restrict__ acc) {
    __shared__ float dt[34][34];
    __shared__ float gt[34][34];
    __shared__ float ssum;
    const int r0 = blockIdx.y * TB;
    const int c0 = blockIdx.x * TB;
    const float* dmap = blockIdx.z ? dispR : dispL;
    const float* gmap = blockIdx.z ? grm : glm;
    const int tid = threadIdx.x;
    if (tid == 0) ssum = 0.0f;

    for (int idx = tid; idx < 34 * 34; idx += 256) {
        int r = idx / 34, c = idx % 34;
        int gi = r0 + r, gj = c0 + c;
        float dv = 0.f, gv = 0.f;
        if (gi < H && gj < W) {
            size_t p = (size_t)gi * W + gj;
            dv = dmap[p]; gv = gmap[p];
        }
        dt[r][c] = dv;
        gt[r][c] = gv;
    }
    __syncthreads();

    float vsum = 0.f;
    for (int idx = tid; idx < TB * TB; idx += 256) {
        int li = idx / TB, lj = idx % TB;
        int gi = r0 + li, gj = c0 + lj;
        if (gi < H - 2 && gj < W - 2) {
            float sd = 0.f, sg = 0.f;
            for (int a = 0; a < 3; ++a)
                for (int b = 0; b < 3; ++b) {
                    sd += dt[li + a][lj + b];
                    sg += gt[li + a][lj + b];
                }
            float lapd = sd - 9.0f * dt[li + 1][lj + 1];
            float lapg = sg - 9.0f * gt[li + 1][lj + 1];
            vsum += expf(-fabsf(lapg)) * fabsf(lapd);
        }
    }

    for (int off = 32; off > 0; off >>= 1) vsum += __shfl_down(vsum, off, 64);
    if ((tid & 63) == 0) atomicAdd(&ssum, vsum);
    __syncthreads();
    if (tid == 0) atomicAdd(&acc[8 + blockIdx.z], (double)ssum);
}

// ---------------------------------------------------------------------------
__global__ void finalize_kernel(const double* __restrict__ acc, float* __restrict__ out) {
    if (threadIdx.x == 0 && blockIdx.x == 0) {
        const double HW = (double)H * (double)W;
        double sadL = acc[0] / (3.0 * HW);
        double sadR = acc[1] / (3.0 * HW);
        double lr1  = acc[2] / HW;
        double lr2  = acc[3] / HW;
        double c3 = (double)(H - 4) * (double)(W - 4);
        double c5 = (double)(H - 8) * (double)(W - 8);
        double ssimL = 0.5 * (acc[4] / c3) + 0.5 * (acc[5] / c5);
        double ssimR = 0.5 * (acc[6] / c3) + 0.5 * (acc[7] / c5);
        double csm = (double)(H - 2) * (double)(W - 2);
        double smooth = acc[8] / csm + acc[9] / csm;
        double rec = 0.5 * ssimL + 0.5 * sadL + 0.5 * ssimR + 0.5 * sadR;
        out[0] = (float)rec;
        out[1] = (float)(0.1 * smooth);
        out[2] = (float)(0.1 * (lr1 + lr2));
    }
}

// ---------------------------------------------------------------------------
extern "C" void kernel_launch(void* const* d_in, const int* in_sizes, int n_in,
                              void* d_out, int out_size, void* d_ws, size_t ws_size,
                              hipStream_t stream) {
    const float* dispL = (const float*)d_in[0];
    const float* dispR = (const float*)d_in[1];
    const float* left  = (const float*)d_in[2];
    const float* right = (const float*)d_in[3];
    float* out = (float*)d_out;

    double* acc = (double*)d_ws;
    float* maps = (float*)((char*)d_ws + 256);
    const size_t HW = (size_t)H * W;
    float* glm  = maps;
    float* grm  = maps + HW;
    float* gelm = maps + 2 * HW;
    float* germ = maps + 3 * HW;

    // zero the 10 double accumulators (ws is re-poisoned to 0xAA each call)
    hipMemsetAsync(d_ws, 0, 256, stream);

    row_kernel<<<H, 256, 0, stream>>>(dispL, dispR, left, right, glm, grm, gelm, germ, acc);

    dim3 gB((W - 4 + TB - 1) / TB, (H - 4 + TB - 1) / TB, 2);
    ssim_kernel<<<gB, 256, 0, stream>>>(glm, gelm, grm, germ, acc);

    dim3 gC((W - 2 + TB - 1) / TB, (H - 2 + TB - 1) / TB, 2);
    smooth_kernel<<<gC, 256, 0, stream>>>(dispL, dispR, glm, grm, acc);

    finalize_kernel<<<1, 64, 0, stream>>>(acc, out);
}

// Round 2
// 212.995 us; speedup vs baseline: 1.6115x; 1.6115x over previous
//
#include <hip/hip_runtime.h>

#define H 1024
#define W 2048
#define WP1f 2049.0f   // W + 1
#define SEG 32
#define NSTRIP 37     // ceil((W-2)/56)
#define NSEGY 8       // 8 blocks.y * 4 waves = 32 segments * SEG(32) = 1024 rows

// ---------------------------------------------------------------------------
__device__ __forceinline__ float sample_row(const float* __restrict__ row, float x) {
    float x0 = floorf(x);
    float x1 = fminf(x0 + 1.0f, WP1f);
    int i0 = (int)x0;
    int i1 = (int)x1;
    float wl = x1 - x;
    float wr = x - x0;
    float pl = (i0 >= 1 && i0 <= W) ? row[i0 - 1] : 0.0f;
    float pr = (i1 >= 1 && i1 <= W) ? row[i1 - 1] : 0.0f;
    return wl * pl + wr * pr;
}

__device__ __forceinline__ float clampx(float x) {
    return fminf(fmaxf(x, 0.0f), WP1f);
}

// ---------------------------------------------------------------------------
// Kernel A: per-row warps + SAD + LR-consistency sums + gray maps.
// rowp[f*1024 + h], f: 0=sadL 1=sadR 2=lr1 3=lr2
__global__ __launch_bounds__(256)
void row_kernel(const float* __restrict__ dispL, const float* __restrict__ dispR,
                const float* __restrict__ left, const float* __restrict__ right,
                float* __restrict__ glm, float* __restrict__ grm,
                float* __restrict__ gelm, float* __restrict__ germ,
                double* __restrict__ rowp) {
    __shared__ float sl[3 * W];
    __shared__ float sr[3 * W];
    __shared__ float sacc[4];
    const int h = blockIdx.x;
    const int tid = threadIdx.x;
    if (tid < 4) sacc[tid] = 0.0f;

    for (int c = 0; c < 3; ++c) {
        const float* Lrow = left + ((size_t)c * H + h) * W;
        const float* Rrow = right + ((size_t)c * H + h) * W;
        for (int j = tid; j < W; j += 256) {
            sl[c * W + j] = Lrow[j];
            sr[c * W + j] = Rrow[j];
        }
    }
    __syncthreads();

    const float* dlrow = dispL + (size_t)h * W;
    const float* drrow = dispR + (size_t)h * W;
    float a_sadL = 0.f, a_sadR = 0.f, a_lr1 = 0.f, a_lr2 = 0.f;

    for (int j = tid; j < W; j += 256) {
        float dl = dlrow[j];
        float dr = drrow[j];
        float xr = clampx((float)(j + 1) + dr);
        float xl = clampx((float)(j + 1) - dl);

        float er0 = sample_row(sl,         xr);
        float er1 = sample_row(sl + W,     xr);
        float er2 = sample_row(sl + 2 * W, xr);
        float el0 = sample_row(sr,         xl);
        float el1 = sample_row(sr + W,     xl);
        float el2 = sample_row(sr + 2 * W, xl);

        float l0 = sl[j], l1 = sl[W + j], l2 = sl[2 * W + j];
        float r0 = sr[j], r1 = sr[W + j], r2 = sr[2 * W + j];

        a_sadL += fabsf(l0 - el0) + fabsf(l1 - el1) + fabsf(l2 - el2);
        a_sadR += fabsf(r0 - er0) + fabsf(r1 - er1) + fabsf(r2 - er2);

        size_t p = (size_t)h * W + j;
        glm[p]  = (l0 + l1 + l2) * (1.0f / 3.0f);
        grm[p]  = (r0 + r1 + r2) * (1.0f / 3.0f);
        gelm[p] = (el0 + el1 + el2) * (1.0f / 3.0f);
        germ[p] = (er0 + er1 + er2) * (1.0f / 3.0f);

        float l2rv = sample_row(dlrow, xr);
        float r2lv = sample_row(drrow, xl);
        a_lr1 += fabsf(r2lv - dl);
        a_lr2 += fabsf(l2rv - dr);
    }

    for (int off = 32; off > 0; off >>= 1) {
        a_sadL += __shfl_down(a_sadL, off, 64);
        a_sadR += __shfl_down(a_sadR, off, 64);
        a_lr1  += __shfl_down(a_lr1,  off, 64);
        a_lr2  += __shfl_down(a_lr2,  off, 64);
    }
    if ((tid & 63) == 0) {
        atomicAdd(&sacc[0], a_sadL);
        atomicAdd(&sacc[1], a_sadR);
        atomicAdd(&sacc[2], a_lr1);
        atomicAdd(&sacc[3], a_lr2);
    }
    __syncthreads();
    if (tid < 4) rowp[tid * 1024 + h] = (double)sacc[tid];
}

// ---------------------------------------------------------------------------
// Kernel B: register-pipeline column sweep. One wave = 56 output columns,
// SEG output rows. Computes SSIM (w=3,5, nested pooling via two cascaded
// box filters) + disparity smoothness, per pair z (0: L, 1: R).
// swp[(z*3+f)*296 + blockLinear], f: 0=ssim3 1=ssim5 2=smooth
__global__ __launch_bounds__(256)
void sweep_kernel(const float* __restrict__ glm, const float* __restrict__ gelm,
                  const float* __restrict__ grm, const float* __restrict__ germ,
                  const float* __restrict__ dispL, const float* __restrict__ dispR,
                  double* __restrict__ swp) {
    __shared__ float sf[3];
    const int tid = threadIdx.x;
    const int wid = tid >> 6, lane = tid & 63;
    if (tid < 3) sf[tid] = 0.f;

    const int z = blockIdx.z;
    const float* X = z ? grm : glm;
    const float* Y = z ? germ : gelm;
    const float* D = z ? dispR : dispL;

    const int q0 = blockIdx.x * 56;
    const int q  = q0 + lane;
    const bool qv = (q < W);
    const int qa = qv ? q : (W - 1);     // clamp address, mask value

    const int seg = blockIdx.y * 4 + wid;
    const int o0 = seg * SEG;
    const int nrows = min(H - o0, SEG + 8);

    const float* px = X + (size_t)o0 * W + qa;
    const float* py = Y + (size_t)o0 * W + qa;
    const float* pd = D + (size_t)o0 * W + qa;

    // raw-value rings
    float xv0=0.f,xv1=0.f,xv2=0.f,xv3=0.f,xv4=0.f;
    float yv0=0.f,yv1=0.f,yv2=0.f,yv3=0.f,yv4=0.f;
    float dv0=0.f,dv1=0.f,dv2=0.f;
    // horizontal-sum rings
    float r3x0=0.f,r3x1=0.f,r3x2=0.f, r3y0=0.f,r3y1=0.f,r3y2=0.f;
    float r5x0=0.f,r5x1=0.f,r5x2=0.f,r5x3=0.f,r5x4=0.f;
    float r5y0=0.f,r5y1=0.f,r5y2=0.f,r5y3=0.f,r5y4=0.f;
    float r3d0=0.f,r3d1=0.f,r3d2=0.f;
    // mu rings
    float m3x0=0.f,m3x1=0.f,m3x2=0.f, m3y0=0.f,m3y1=0.f,m3y2=0.f;
    float m5x0=0.f,m5x1=0.f,m5x2=0.f,m5x3=0.f,m5x4=0.f;
    float m5y0=0.f,m5y1=0.f,m5y2=0.f,m5y3=0.f,m5y4=0.f;
    // product horizontal-sum rings
    float q3xx0=0.f,q3xx1=0.f,q3xx2=0.f;
    float q3yy0=0.f,q3yy1=0.f,q3yy2=0.f;
    float q3xy0=0.f,q3xy1=0.f,q3xy2=0.f;
    float q5xx0=0.f,q5xx1=0.f,q5xx2=0.f,q5xx3=0.f,q5xx4=0.f;
    float q5yy0=0.f,q5yy1=0.f,q5yy2=0.f,q5yy3=0.f,q5yy4=0.f;
    float q5xy0=0.f,q5xy1=0.f,q5xy2=0.f,q5xy3=0.f,q5xy4=0.f;

    float accS=0.f, acc3=0.f, acc5=0.f;
    const float C1 = 1e-4f, C2 = 9e-4f;

    for (int n = 0; n < nrows; ++n) {
        float xv = qv ? *px : 0.f; px += W;
        float yv = qv ? *py : 0.f; py += W;
        float dv = qv ? *pd : 0.f; pd += W;
        xv0=xv1; xv1=xv2; xv2=xv3; xv3=xv4; xv4=xv;
        yv0=yv1; yv1=yv2; yv2=yv3; yv3=yv4; yv4=yv;
        dv0=dv1; dv1=dv2; dv2=dv;

        float h3x = xv + __shfl_down(xv,1,64) + __shfl_down(xv,2,64);
        float h5x = h3x + __shfl_down(xv,3,64) + __shfl_down(xv,4,64);
        float h3y = yv + __shfl_down(yv,1,64) + __shfl_down(yv,2,64);
        float h5y = h3y + __shfl_down(yv,3,64) + __shfl_down(yv,4,64);
        float h3d = dv + __shfl_down(dv,1,64) + __shfl_down(dv,2,64);

        r3x0=r3x1; r3x1=r3x2; r3x2=h3x;
        r3y0=r3y1; r3y1=r3y2; r3y2=h3y;
        r5x0=r5x1; r5x1=r5x2; r5x2=r5x3; r5x3=r5x4; r5x4=h5x;
        r5y0=r5y1; r5y1=r5y2; r5y2=r5y3; r5y3=r5y4; r5y4=h5y;
        r3d0=r3d1; r3d1=r3d2; r3d2=h3d;

        if (n >= 2) {
            // mu3 at row r-2; t3 at row r-2
            float s3x = r3x0 + r3x1 + r3x2;
            float s3y = r3y0 + r3y1 + r3y2;
            float mu3x = s3x * (1.f/9.f), mu3y = s3y * (1.f/9.f);
            m3x0=m3x1; m3x1=m3x2; m3x2=mu3x;
            m3y0=m3y1; m3y1=m3y2; m3y2=mu3y;
            float xc1 = __shfl_down(xv3,1,64);   // x[r-1][q+1]
            float yc1 = __shfl_down(yv3,1,64);
            float t3x = xc1 - mu3x, t3y = yc1 - mu3y;
            float pxx = t3x*t3x, pyy = t3y*t3y, pxy = t3x*t3y;
            float hxx = pxx + __shfl_down(pxx,1,64) + __shfl_down(pxx,2,64);
            float hyy = pyy + __shfl_down(pyy,1,64) + __shfl_down(pyy,2,64);
            float hxy = pxy + __shfl_down(pxy,1,64) + __shfl_down(pxy,2,64);
            q3xx0=q3xx1; q3xx1=q3xx2; q3xx2=hxx;
            q3yy0=q3yy1; q3yy1=q3yy2; q3yy2=hyy;
            q3xy0=q3xy1; q3xy1=q3xy2; q3xy2=hxy;

            // smoothness at row r-2 (Laplacian 3x3): shuffles unconditional
            float cd = __shfl_down(dv1,1,64);    // d[r-1][q+1]
            float s9d = r3d0 + r3d1 + r3d2;
            float lapd = s9d - 9.f*cd;
            float lapg = s3x - 9.f*xc1;
            float sv = expf(-fabsf(lapg)) * fabsf(lapd);
            if ((n - 2) < SEG && lane < 56 && q <= W-3) accS += sv;
        }

        if (n >= 4) {
            // mu5 at row r-4; t5 at row r-4
            float mu5x = (r5x0+r5x1+r5x2+r5x3+r5x4) * (1.f/25.f);
            float mu5y = (r5y0+r5y1+r5y2+r5y3+r5y4) * (1.f/25.f);
            m5x0=m5x1; m5x1=m5x2; m5x2=m5x3; m5x3=m5x4; m5x4=mu5x;
            m5y0=m5y1; m5y1=m5y2; m5y2=m5y3; m5y3=m5y4; m5y4=mu5y;
            float t5x = __shfl_down(xv2,2,64) - mu5x;   // x[r-2][q+2]
            float t5y = __shfl_down(yv2,2,64) - mu5y;
            float Pxx = t5x*t5x, Pyy = t5y*t5y, Pxy = t5x*t5y;
            float Hxx = Pxx + __shfl_down(Pxx,1,64) + __shfl_down(Pxx,2,64)
                            + __shfl_down(Pxx,3,64) + __shfl_down(Pxx,4,64);
            float Hyy = Pyy + __shfl_down(Pyy,1,64) + __shfl_down(Pyy,2,64)
                            + __shfl_down(Pyy,3,64) + __shfl_down(Pyy,4,64);
            float Hxy = Pxy + __shfl_down(Pxy,1,64) + __shfl_down(Pxy,2,64)
                            + __shfl_down(Pxy,3,64) + __shfl_down(Pxy,4,64);
            q5xx0=q5xx1; q5xx1=q5xx2; q5xx2=q5xx3; q5xx3=q5xx4; q5xx4=Hxx;
            q5yy0=q5yy1; q5yy1=q5yy2; q5yy2=q5yy3; q5yy3=q5yy4; q5yy4=Hyy;
            q5xy0=q5xy1; q5xy1=q5xy2; q5xy2=q5xy3; q5xy3=q5xy4; q5xy4=Hxy;

            // ssim w=3 at row s3 = r-4
            float cx = __shfl_down(m3x1,1,64);   // mu3[r-3][q+1]
            float cy = __shfl_down(m3y1,1,64);
            float sxx = (q3xx0+q3xx1+q3xx2) * (1.f/9.f);
            float syy = (q3yy0+q3yy1+q3yy2) * (1.f/9.f);
            float sxy = (q3xy0+q3xy1+q3xy2) * (1.f/9.f);
            float nn = (2.f*cx*cy + C1) * (2.f*sxy + C2);
            float dd = (cx*cx + cy*cy + C1) * (sxx + syy + C2);
            float val = fminf(fmaxf(1.f - nn/dd, 0.f), 2.f);
            if ((n - 4) < SEG && lane < 56 && q <= W-5) acc3 += val;
        }

        if (n >= 8) {
            // ssim w=5 at row s5 = r-8
            float cx = __shfl_down(m5x2,2,64);   // mu5[r-6][q+2]
            float cy = __shfl_down(m5y2,2,64);
            float sxx = (q5xx0+q5xx1+q5xx2+q5xx3+q5xx4) * (1.f/25.f);
            float syy = (q5yy0+q5yy1+q5yy2+q5yy3+q5yy4) * (1.f/25.f);
            float sxy = (q5xy0+q5xy1+q5xy2+q5xy3+q5xy4) * (1.f/25.f);
            float nn = (2.f*cx*cy + C1) * (2.f*sxy + C2);
            float dd = (cx*cx + cy*cy + C1) * (sxx + syy + C2);
            float val = fminf(fmaxf(1.f - nn/dd, 0.f), 2.f);
            if (lane < 56 && q <= W-9) acc5 += val;
        }
    }

    for (int off = 32; off > 0; off >>= 1) {
        acc3 += __shfl_down(acc3, off, 64);
        acc5 += __shfl_down(acc5, off, 64);
        accS += __shfl_down(accS, off, 64);
    }
    __syncthreads();
    if (lane == 0) {
        atomicAdd(&sf[0], acc3);
        atomicAdd(&sf[1], acc5);
        atomicAdd(&sf[2], accS);
    }
    __syncthreads();
    if (tid == 0) {
        int b = blockIdx.y * gridDim.x + blockIdx.x;   // [0, 296)
        swp[((size_t)z*3 + 0)*296 + b] = (double)sf[0];
        swp[((size_t)z*3 + 1)*296 + b] = (double)sf[1];
        swp[((size_t)z*3 + 2)*296 + b] = (double)sf[2];
    }
}

// ---------------------------------------------------------------------------
__global__ void finalize_kernel(const double* __restrict__ rowp,
                                const double* __restrict__ swp,
                                float* __restrict__ out) {
    const int lane = threadIdx.x;   // 64 threads
    double s[10];
#pragma unroll
    for (int f = 0; f < 4; ++f) {
        double a = 0.0;
        for (int i = lane; i < 1024; i += 64) a += rowp[f*1024 + i];
        for (int off = 32; off > 0; off >>= 1) a += __shfl_down(a, off, 64);
        s[f] = a;
    }
#pragma unroll
    for (int k = 0; k < 6; ++k) {
        double a = 0.0;
        for (int i = lane; i < 296; i += 64) a += swp[k*296 + i];
        for (int off = 32; off > 0; off >>= 1) a += __shfl_down(a, off, 64);
        s[4+k] = a;
    }
    if (lane == 0) {
        const double HW = (double)H * (double)W;
        double sadL = s[0] / (3.0 * HW);
        double sadR = s[1] / (3.0 * HW);
        double lr   = (s[2] + s[3]) / HW;
        const double c3  = (double)(H-4) * (double)(W-4);
        const double c5  = (double)(H-8) * (double)(W-8);
        const double csm = (double)(H-2) * (double)(W-2);
        // swp order: z0: ssim3, ssim5, smooth ; z1: ssim3, ssim5, smooth
        double ssimL = 0.5 * s[4] / c3 + 0.5 * s[5] / c5;
        double ssimR = 0.5 * s[7] / c3 + 0.5 * s[8] / c5;
        double rec = 0.5 * ssimL + 0.5 * sadL + 0.5 * ssimR + 0.5 * sadR;
        double smooth = (s[6] + s[9]) / csm;
        out[0] = (float)rec;
        out[1] = (float)(0.1 * smooth);
        out[2] = (float)(0.1 * lr);
    }
}

// ---------------------------------------------------------------------------
extern "C" void kernel_launch(void* const* d_in, const int* in_sizes, int n_in,
                              void* d_out, int out_size, void* d_ws, size_t ws_size,
                              hipStream_t stream) {
    const float* dispL = (const float*)d_in[0];
    const float* dispR = (const float*)d_in[1];
    const float* left  = (const float*)d_in[2];
    const float* right = (const float*)d_in[3];
    float* out = (float*)d_out;

    double* rowp = (double*)d_ws;            // 4*1024 doubles
    double* swp  = rowp + 4096;              // 6*296 doubles
    float* maps  = (float*)(swp + 6*296);
    const size_t HW = (size_t)H * W;
    float* glm  = maps;
    float* grm  = maps + HW;
    float* gelm = maps + 2*HW;
    float* germ = maps + 3*HW;

    // every partial slot is written unconditionally each call -> no memset needed
    row_kernel<<<H, 256, 0, stream>>>(dispL, dispR, left, right, glm, grm, gelm, germ, rowp);
    sweep_kernel<<<dim3(NSTRIP, NSEGY, 2), 256, 0, stream>>>(glm, gelm, grm, germ, dispL, dispR, swp);
    finalize_kernel<<<1, 64, 0, stream>>>(rowp, swp, out);
}

// Round 7
// 196.569 us; speedup vs baseline: 1.7461x; 1.0836x over previous
//
#include <hip/hip_runtime.h>

#define H 1024
#define W 2048
#define HWsz ((size_t)H * (size_t)W)
#define WP1f 2049.0f   // W + 1

#define STRIDE 248
#define NSTRIPS 9      // 9*248 = 2232 >= 2048
#define S3SEG 8
#define S3ROWS (S3SEG + 4)
#define S3BLKY 32      // 32 blocks.y * 4 waves = 128 segments * 8 = 1024 rows
#define NB3 (NSTRIPS * S3BLKY)   // 288 blocks per z
#define S5SEG 16
#define S5ROWS (S5SEG + 8)
#define S5BLKY 16      // 16 * 4 waves = 64 segments * 16 = 1024 rows
#define NB5 (NSTRIPS * S5BLKY)   // 144 blocks per z
#define NBW (8 * 1024) // warp_kernel blocks

// ---------------------------------------------------------------------------
__device__ __forceinline__ float wred(float v) {
#pragma unroll
    for (int off = 32; off > 0; off >>= 1) v += __shfl_down(v, off, 64);
    return v;
}

__device__ __forceinline__ float sample_row(const float* __restrict__ row, float x) {
    float x0 = floorf(x);
    float x1 = fminf(x0 + 1.0f, WP1f);
    int i0 = (int)x0;
    int i1 = (int)x1;
    float wl = x1 - x;
    float wr = x - x0;
    float pl = (i0 >= 1 && i0 <= W) ? row[i0 - 1] : 0.0f;
    float pr = (i1 >= 1 && i1 <= W) ? row[i1 - 1] : 0.0f;
    return wl * pl + wr * pr;
}

__device__ __forceinline__ float clampx(float x) {
    return fminf(fmaxf(x, 0.0f), WP1f);
}

// ---------------------------------------------------------------------------
// Kernel A: warps + SAD + LR sums + gray maps. No LDS tiles: disparity <= 64
// keeps gathers row-local (L1/L2-resident). 1 col/thread, grid (W/256, H).
// rp[f*NBW + b], f: 0=sadL 1=sadR 2=lr1 3=lr2
__global__ __launch_bounds__(256)
void warp_kernel(const float* __restrict__ dispL, const float* __restrict__ dispR,
                 const float* __restrict__ left, const float* __restrict__ right,
                 float* __restrict__ glm, float* __restrict__ grm,
                 float* __restrict__ gelm, float* __restrict__ germ,
                 float* __restrict__ rp) {
    __shared__ float sb[4];
    const int tid = threadIdx.x;
    if (tid < 4) sb[tid] = 0.f;
    __syncthreads();

    const int h = blockIdx.y;
    const int j = blockIdx.x * 256 + tid;
    const float* Lr  = left  + (size_t)h * W;
    const float* Rr  = right + (size_t)h * W;
    const float* dlr = dispL + (size_t)h * W;
    const float* drr = dispR + (size_t)h * W;

    float dl = dlr[j], dr = drr[j];
    float xr = clampx((float)(j + 1) + dr);  // sample position into LEFT
    float xl = clampx((float)(j + 1) - dl);  // sample position into RIGHT

    float er0 = sample_row(Lr,           xr);
    float er1 = sample_row(Lr + HWsz,    xr);
    float er2 = sample_row(Lr + 2*HWsz,  xr);
    float el0 = sample_row(Rr,           xl);
    float el1 = sample_row(Rr + HWsz,    xl);
    float el2 = sample_row(Rr + 2*HWsz,  xl);

    float l0 = Lr[j], l1 = Lr[HWsz + j], l2 = Lr[2*HWsz + j];
    float r0 = Rr[j], r1 = Rr[HWsz + j], r2 = Rr[2*HWsz + j];

    float sadL = fabsf(l0-el0) + fabsf(l1-el1) + fabsf(l2-el2);
    float sadR = fabsf(r0-er0) + fabsf(r1-er1) + fabsf(r2-er2);

    size_t p = (size_t)h * W + j;
    glm[p]  = (l0 + l1 + l2) * (1.0f/3.0f);
    grm[p]  = (r0 + r1 + r2) * (1.0f/3.0f);
    gelm[p] = (el0 + el1 + el2) * (1.0f/3.0f);
    germ[p] = (er0 + er1 + er2) * (1.0f/3.0f);

    float l2rv = sample_row(dlr, xr);
    float r2lv = sample_row(drr, xl);
    float lr1 = fabsf(r2lv - dl);
    float lr2 = fabsf(l2rv - dr);

    sadL = wred(sadL); sadR = wred(sadR); lr1 = wred(lr1); lr2 = wred(lr2);
    if ((tid & 63) == 0) {
        atomicAdd(&sb[0], sadL); atomicAdd(&sb[1], sadR);
        atomicAdd(&sb[2], lr1);  atomicAdd(&sb[3], lr2);
    }
    __syncthreads();
    const int b = blockIdx.y * gridDim.x + blockIdx.x;
    if (tid < 4) rp[tid * NBW + b] = sb[tid];
}

// ---------------------------------------------------------------------------
// Kernel B: ssim w=3 + disparity smoothness. V=4 cols/lane, vertical-sum-first
// register pipeline. One wave = one 8-row segment of a 248-col strip.
__global__ __launch_bounds__(256)
void s3_kernel(const float* __restrict__ glm, const float* __restrict__ gelm,
               const float* __restrict__ grm, const float* __restrict__ germ,
               const float* __restrict__ dispL, const float* __restrict__ dispR,
               float* __restrict__ s3p, float* __restrict__ smp) {
    __shared__ float sb[2];
    const int tid = threadIdx.x, wid = tid >> 6, lane = tid & 63;
    if (tid < 2) sb[tid] = 0.f;
    __syncthreads();

    const int z = blockIdx.z;
    const float* X = z ? grm  : glm;
    const float* Y = z ? germ : gelm;
    const float* D = z ? dispR : dispL;
    const int C0 = blockIdx.x * STRIDE;
    const int cb = C0 + 4 * lane;
    const int cba = min(cb, W - 4);
    const int o0 = (blockIdx.y * 4 + wid) * S3SEG;

    float xr_[3][4], yr_[3][4], dr_[3][4];
    float hxx[3][4], hyy[3][4], hxy[3][4];
    float m3x[2][4], m3y[2][4];
    float acc3 = 0.f, accS = 0.f;
    const float C1 = 1e-4f, C2 = 9e-4f;

    for (int n = 0; n < S3ROWS; ++n) {
        const int r = o0 + n;
        const int ra = min(r, H - 1);
        const float4 xv = *(const float4*)(X + (size_t)ra * W + cba);
        const float4 yv = *(const float4*)(Y + (size_t)ra * W + cba);
        const float4 dv = *(const float4*)(D + (size_t)ra * W + cba);
#pragma unroll
        for (int t = 0; t < 2; ++t)
#pragma unroll
            for (int k = 0; k < 4; ++k) {
                xr_[t][k] = xr_[t+1][k]; yr_[t][k] = yr_[t+1][k]; dr_[t][k] = dr_[t+1][k];
            }
        xr_[2][0] = xv.x; xr_[2][1] = xv.y; xr_[2][2] = xv.z; xr_[2][3] = xv.w;
        yr_[2][0] = yv.x; yr_[2][1] = yv.y; yr_[2][2] = yv.z; yr_[2][3] = yv.w;
        dr_[2][0] = dv.x; dr_[2][1] = dv.y; dr_[2][2] = dv.z; dr_[2][3] = dv.w;

        if (n >= 2) {
            float v3x[6], v3y[6], v3d[6];
#pragma unroll
            for (int k = 0; k < 4; ++k) {
                v3x[k] = xr_[0][k] + xr_[1][k] + xr_[2][k];
                v3y[k] = yr_[0][k] + yr_[1][k] + yr_[2][k];
                v3d[k] = dr_[0][k] + dr_[1][k] + dr_[2][k];
            }
            v3x[4] = __shfl_down(v3x[0],1,64); v3x[5] = __shfl_down(v3x[1],1,64);
            v3y[4] = __shfl_down(v3y[0],1,64); v3y[5] = __shfl_down(v3y[1],1,64);
            v3d[4] = __shfl_down(v3d[0],1,64); v3d[5] = __shfl_down(v3d[1],1,64);
            float xe = __shfl_down(xr_[1][0],1,64);
            float ye = __shfl_down(yr_[1][0],1,64);
            float de = __shfl_down(dr_[1][0],1,64);
            float xc[4] = {xr_[1][1], xr_[1][2], xr_[1][3], xe};   // x[r-1][cb+k+1]
            float yc[4] = {yr_[1][1], yr_[1][2], yr_[1][3], ye};
            float dc[4] = {dr_[1][1], dr_[1][2], dr_[1][3], de};

            float s3xv[4], mu3xv[4], mu3yv[4];
#pragma unroll
            for (int k = 0; k < 4; ++k) {
                s3xv[k] = v3x[k] + v3x[k+1] + v3x[k+2];
                mu3xv[k] = s3xv[k] * (1.f/9.f);
                mu3yv[k] = (v3y[k] + v3y[k+1] + v3y[k+2]) * (1.f/9.f);
            }
            float uxx[6], uyy[6], uxy[6];
#pragma unroll
            for (int k = 0; k < 4; ++k) {
                float tx = xc[k] - mu3xv[k], ty = yc[k] - mu3yv[k];
                uxx[k] = tx*tx; uyy[k] = ty*ty; uxy[k] = tx*ty;
            }
            uxx[4] = __shfl_down(uxx[0],1,64); uxx[5] = __shfl_down(uxx[1],1,64);
            uyy[4] = __shfl_down(uyy[0],1,64); uyy[5] = __shfl_down(uyy[1],1,64);
            uxy[4] = __shfl_down(uxy[0],1,64); uxy[5] = __shfl_down(uxy[1],1,64);
#pragma unroll
            for (int t = 0; t < 2; ++t)
#pragma unroll
                for (int k = 0; k < 4; ++k) {
                    hxx[t][k] = hxx[t+1][k]; hyy[t][k] = hyy[t+1][k]; hxy[t][k] = hxy[t+1][k];
                }
#pragma unroll
            for (int k = 0; k < 4; ++k) {
                hxx[2][k] = uxx[k] + uxx[k+1] + uxx[k+2];
                hyy[2][k] = uyy[k] + uyy[k+1] + uyy[k+2];
                hxy[2][k] = uxy[k] + uxy[k+1] + uxy[k+2];
                m3x[0][k] = m3x[1][k]; m3x[1][k] = mu3xv[k];
                m3y[0][k] = m3y[1][k]; m3y[1][k] = mu3yv[k];
            }
            const int i = r - 2;
            if ((n - 2) < S3SEG && i < H - 2) {
#pragma unroll
                for (int k = 0; k < 4; ++k) {
                    if (4*lane + k < STRIDE && cb + k <= W - 3) {
                        float lapd = (v3d[k] + v3d[k+1] + v3d[k+2]) - 9.f * dc[k];
                        float lapg = s3xv[k] - 9.f * xc[k];
                        accS += expf(-fabsf(lapg)) * fabsf(lapd);
                    }
                }
            }
        }
        if (n >= 4) {
            const int s = r - 4;
            if ((n - 4) < S3SEG && s < H - 4) {
                float cxe = __shfl_down(m3x[0][0],1,64);
                float cye = __shfl_down(m3y[0][0],1,64);
#pragma unroll
                for (int k = 0; k < 4; ++k) {
                    float cx = (k < 3) ? m3x[0][k+1] : cxe;   // mu3[s+1][t+1]
                    float cy = (k < 3) ? m3y[0][k+1] : cye;
                    float sxx = (hxx[0][k] + hxx[1][k] + hxx[2][k]) * (1.f/9.f);
                    float syy = (hyy[0][k] + hyy[1][k] + hyy[2][k]) * (1.f/9.f);
                    float sxy = (hxy[0][k] + hxy[1][k] + hxy[2][k]) * (1.f/9.f);
                    float nn = (2.f*cx*cy + C1) * (2.f*sxy + C2);
                    float dd = (cx*cx + cy*cy + C1) * (sxx + syy + C2);
                    float val = fminf(fmaxf(1.f - nn/dd, 0.f), 2.f);
                    if (4*lane + k < STRIDE && cb + k <= W - 5) acc3 += val;
                }
            }
        }
    }
    acc3 = wred(acc3); accS = wred(accS);
    if (lane == 0) { atomicAdd(&sb[0], acc3); atomicAdd(&sb[1], accS); }
    __syncthreads();
    const int b = blockIdx.y * NSTRIPS + blockIdx.x;
    if (tid == 0) { s3p[z*NB3 + b] = sb[0]; smp[z*NB3 + b] = sb[1]; }
}

// ---------------------------------------------------------------------------
// Kernel C: ssim w=5, same structure (halo 8 rows).
__global__ __launch_bounds__(256)
void s5_kernel(const float* __restrict__ glm, const float* __restrict__ gelm,
               const float* __restrict__ grm, const float* __restrict__ germ,
               float* __restrict__ s5p) {
    __shared__ float sb[1];
    const int tid = threadIdx.x, wid = tid >> 6, lane = tid & 63;
    if (tid == 0) sb[0] = 0.f;
    __syncthreads();

    const int z = blockIdx.z;
    const float* X = z ? grm  : glm;
    const float* Y = z ? germ : gelm;
    const int C0 = blockIdx.x * STRIDE;
    const int cb = C0 + 4 * lane;
    const int cba = min(cb, W - 4);
    const int o0 = (blockIdx.y * 4 + wid) * S5SEG;

    float xr_[5][4], yr_[5][4];
    float hxx[5][4], hyy[5][4], hxy[5][4];
    float m5x[3][4], m5y[3][4];
    float acc5 = 0.f;
    const float C1 = 1e-4f, C2 = 9e-4f;

    for (int n = 0; n < S5ROWS; ++n) {
        const int r = o0 + n;
        const int ra = min(r, H - 1);
        const float4 xv = *(const float4*)(X + (size_t)ra * W + cba);
        const float4 yv = *(const float4*)(Y + (size_t)ra * W + cba);
#pragma unroll
        for (int t = 0; t < 4; ++t)
#pragma unroll
            for (int k = 0; k < 4; ++k) { xr_[t][k] = xr_[t+1][k]; yr_[t][k] = yr_[t+1][k]; }
        xr_[4][0] = xv.x; xr_[4][1] = xv.y; xr_[4][2] = xv.z; xr_[4][3] = xv.w;
        yr_[4][0] = yv.x; yr_[4][1] = yv.y; yr_[4][2] = yv.z; yr_[4][3] = yv.w;

        if (n >= 4) {
            float v5x[8], v5y[8];
#pragma unroll
            for (int k = 0; k < 4; ++k) {
                v5x[k] = xr_[0][k] + xr_[1][k] + xr_[2][k] + xr_[3][k] + xr_[4][k];
                v5y[k] = yr_[0][k] + yr_[1][k] + yr_[2][k] + yr_[3][k] + yr_[4][k];
            }
#pragma unroll
            for (int k = 0; k < 4; ++k) {
                v5x[4+k] = __shfl_down(v5x[k],1,64);
                v5y[4+k] = __shfl_down(v5y[k],1,64);
            }
            float mu5xv[4], mu5yv[4];
#pragma unroll
            for (int k = 0; k < 4; ++k) {
                mu5xv[k] = (v5x[k]+v5x[k+1]+v5x[k+2]+v5x[k+3]+v5x[k+4]) * (1.f/25.f);
                mu5yv[k] = (v5y[k]+v5y[k+1]+v5y[k+2]+v5y[k+3]+v5y[k+4]) * (1.f/25.f);
            }
            float xe0 = __shfl_down(xr_[2][0],1,64), xe1 = __shfl_down(xr_[2][1],1,64);
            float ye0 = __shfl_down(yr_[2][0],1,64), ye1 = __shfl_down(yr_[2][1],1,64);
            float xc[4] = {xr_[2][2], xr_[2][3], xe0, xe1};   // x[p+2][t+2]
            float yc[4] = {yr_[2][2], yr_[2][3], ye0, ye1};
            float uxx[8], uyy[8], uxy[8];
#pragma unroll
            for (int k = 0; k < 4; ++k) {
                float tx = xc[k] - mu5xv[k], ty = yc[k] - mu5yv[k];
                uxx[k] = tx*tx; uyy[k] = ty*ty; uxy[k] = tx*ty;
            }
#pragma unroll
            for (int k = 0; k < 4; ++k) {
                uxx[4+k] = __shfl_down(uxx[k],1,64);
                uyy[4+k] = __shfl_down(uyy[k],1,64);
                uxy[4+k] = __shfl_down(uxy[k],1,64);
            }
#pragma unroll
            for (int t = 0; t < 4; ++t)
#pragma unroll
                for (int k = 0; k < 4; ++k) {
                    hxx[t][k] = hxx[t+1][k]; hyy[t][k] = hyy[t+1][k]; hxy[t][k] = hxy[t+1][k];
                }
#pragma unroll
            for (int k = 0; k < 4; ++k) {
                hxx[4][k] = uxx[k]+uxx[k+1]+uxx[k+2]+uxx[k+3]+uxx[k+4];
                hyy[4][k] = uyy[k]+uyy[k+1]+uyy[k+2]+uyy[k+3]+uyy[k+4];
                hxy[4][k] = uxy[k]+uxy[k+1]+uxy[k+2]+uxy[k+3]+uxy[k+4];
                m5x[0][k] = m5x[1][k]; m5x[1][k] = m5x[2][k]; m5x[2][k] = mu5xv[k];
                m5y[0][k] = m5y[1][k]; m5y[1][k] = m5y[2][k]; m5y[2][k] = mu5yv[k];
            }
        }
        if (n >= 8) {
            const int s = r - 8;
            if ((n - 8) < S5SEG && s < H - 8) {
                float ce0x = __shfl_down(m5x[0][0],1,64), ce1x = __shfl_down(m5x[0][1],1,64);
                float ce0y = __shfl_down(m5y[0][0],1,64), ce1y = __shfl_down(m5y[0][1],1,64);
#pragma unroll
                for (int k = 0; k < 4; ++k) {
                    float cx = (k < 2) ? m5x[0][k+2] : ((k == 2) ? ce0x : ce1x);  // mu5[s+2][t+2]
                    float cy = (k < 2) ? m5y[0][k+2] : ((k == 2) ? ce0y : ce1y);
                    float sxx = (hxx[0][k]+hxx[1][k]+hxx[2][k]+hxx[3][k]+hxx[4][k]) * (1.f/25.f);
                    float syy = (hyy[0][k]+hyy[1][k]+hyy[2][k]+hyy[3][k]+hyy[4][k]) * (1.f/25.f);
                    float sxy = (hxy[0][k]+hxy[1][k]+hxy[2][k]+hxy[3][k]+hxy[4][k]) * (1.f/25.f);
                    float nn = (2.f*cx*cy + C1) * (2.f*sxy + C2);
                    float dd = (cx*cx + cy*cy + C1) * (sxx + syy + C2);
                    float val = fminf(fmaxf(1.f - nn/dd, 0.f), 2.f);
                    if (4*lane + k < STRIDE && cb + k <= W - 9) acc5 += val;
                }
            }
        }
    }
    acc5 = wred(acc5);
    if (lane == 0) atomicAdd(&sb[0], acc5);
    __syncthreads();
    const int b = blockIdx.y * NSTRIPS + blockIdx.x;
    if (tid == 0) s5p[z*NB5 + b] = sb[0];
}

// ---------------------------------------------------------------------------
__global__ __launch_bounds__(1024)
void finalize_kernel(const float* __restrict__ rp, const float* __restrict__ s3p,
                     const float* __restrict__ smp, const float* __restrict__ s5p,
                     float* __restrict__ out) {
    __shared__ double sums[10];
    const int tid = threadIdx.x;
    if (tid < 10) sums[tid] = 0.0;
    __syncthreads();

    double a[10] = {0,0,0,0,0,0,0,0,0,0};
#pragma unroll
    for (int f = 0; f < 4; ++f)
        for (int i = tid; i < NBW; i += 1024) a[f] += (double)rp[f*NBW + i];
#pragma unroll
    for (int z = 0; z < 2; ++z) {
        for (int i = tid; i < NB3; i += 1024) a[4+z] += (double)s3p[z*NB3 + i];
        for (int i = tid; i < NB3; i += 1024) a[6+z] += (double)smp[z*NB3 + i];
        for (int i = tid; i < NB5; i += 1024) a[8+z] += (double)s5p[z*NB5 + i];
    }
#pragma unroll
    for (int f = 0; f < 10; ++f) {
        double v = a[f];
        for (int off = 32; off > 0; off >>= 1) v += __shfl_down(v, off, 64);
        if ((tid & 63) == 0) atomicAdd(&sums[f], v);
    }
    __syncthreads();
    if (tid == 0) {
        const double HW = (double)H * (double)W;
        double sadL = sums[0] / (3.0 * HW);
        double sadR = sums[1] / (3.0 * HW);
        double lr   = (sums[2] + sums[3]) / HW;
        const double c3  = (double)(H-4) * (double)(W-4);
        const double c5  = (double)(H-8) * (double)(W-8);
        const double csm = (double)(H-2) * (double)(W-2);
        double ssimL = 0.5 * sums[4] / c3 + 0.5 * sums[8] / c5;
        double ssimR = 0.5 * sums[5] / c3 + 0.5 * sums[9] / c5;
        double rec = 0.5 * ssimL + 0.5 * sadL + 0.5 * ssimR + 0.5 * sadR;
        double smooth = (sums[6] + sums[7]) / csm;
        out[0] = (float)rec;
        out[1] = (float)(0.1 * smooth);
        out[2] = (float)(0.1 * lr);
    }
}

// ---------------------------------------------------------------------------
extern "C" void kernel_launch(void* const* d_in, const int* in_sizes, int n_in,
                              void* d_out, int out_size, void* d_ws, size_t ws_size,
                              hipStream_t stream) {
    const float* dispL = (const float*)d_in[0];
    const float* dispR = (const float*)d_in[1];
    const float* left  = (const float*)d_in[2];
    const float* right = (const float*)d_in[3];
    float* out = (float*)d_out;

    float* rp  = (float*)d_ws;          // 4*8192
    float* s3p = rp  + 4*NBW;           // 2*288
    float* smp = s3p + 2*NB3;           // 2*288
    float* s5p = smp + 2*NB3;           // 2*144
    float* maps = s5p + 2*NB5;          // offset 136832 B, 16-aligned
    float* glm  = maps;
    float* grm  = maps + HWsz;
    float* gelm = maps + 2*HWsz;
    float* germ = maps + 3*HWsz;

    warp_kernel<<<dim3(8, 1024), 256, 0, stream>>>(dispL, dispR, left, right,
                                                   glm, grm, gelm, germ, rp);
    s3_kernel<<<dim3(NSTRIPS, S3BLKY, 2), 256, 0, stream>>>(glm, gelm, grm, germ,
                                                            dispL, dispR, s3p, smp);
    s5_kernel<<<dim3(NSTRIPS, S5BLKY, 2), 256, 0, stream>>>(glm, gelm, grm, germ, s5p);
    finalize_kernel<<<1, 1024, 0, stream>>>(rp, s3p, smp, s5p, out);
}

// Round 8
// 186.175 us; speedup vs baseline: 1.8436x; 1.0558x over previous
//
#include <hip/hip_runtime.h>

#define H 1024
#define W 2048
#define HWsz ((size_t)H * (size_t)W)
#define WP1f 2049.0f   // W + 1

#define STRIDE 248
#define NSTRIPS 9      // 9*248 = 2232 >= 2048
#define S3SEG 8
#define S3ROWS (S3SEG + 4)
#define S3BLKY 32      // 32 blocks.y * 4 waves = 128 segments * 8 = 1024 rows
#define NB3 (NSTRIPS * S3BLKY)   // 288 blocks per z
#define S5SEG 8        // was 16: halved -> 2304 waves (2.25/SIMD) for latency hiding
#define S5ROWS (S5SEG + 8)
#define S5BLKY 32      // 32 * 4 waves = 128 segments * 8 = 1024 rows
#define NB5 (NSTRIPS * S5BLKY)   // 288 blocks per z
#define NBW (4 * 1024) // warp_kernel blocks (2 cols/thread)

// ---------------------------------------------------------------------------
__device__ __forceinline__ float wred(float v) {
#pragma unroll
    for (int off = 32; off > 0; off >>= 1) v += __shfl_down(v, off, 64);
    return v;
}

__device__ __forceinline__ float sample_row(const float* __restrict__ row, float x) {
    float x0 = floorf(x);
    float x1 = fminf(x0 + 1.0f, WP1f);
    int i0 = (int)x0;
    int i1 = (int)x1;
    float wl = x1 - x;
    float wr = x - x0;
    float pl = (i0 >= 1 && i0 <= W) ? row[i0 - 1] : 0.0f;
    float pr = (i1 >= 1 && i1 <= W) ? row[i1 - 1] : 0.0f;
    return wl * pl + wr * pr;
}

__device__ __forceinline__ float clampx(float x) {
    return fminf(fmaxf(x, 0.0f), WP1f);
}

// ---------------------------------------------------------------------------
// Kernel A: warps + SAD + LR sums + gray maps. 2 cols/thread, float2 I/O for
// all contiguous traffic; gathers stay scalar but dual-column ILP hides L1/L2
// latency. Grid (4, 1024). rp[f*NBW + b], f: 0=sadL 1=sadR 2=lr1 3=lr2
__global__ __launch_bounds__(256)
void warp_kernel(const float* __restrict__ dispL, const float* __restrict__ dispR,
                 const float* __restrict__ left, const float* __restrict__ right,
                 float* __restrict__ glm, float* __restrict__ grm,
                 float* __restrict__ gelm, float* __restrict__ germ,
                 float* __restrict__ rp) {
    __shared__ float sb[4];
    const int tid = threadIdx.x;
    if (tid < 4) sb[tid] = 0.f;
    __syncthreads();

    const int h = blockIdx.y;
    const int j0 = (blockIdx.x * 256 + tid) * 2;
    const float* Lr  = left  + (size_t)h * W;
    const float* Rr  = right + (size_t)h * W;
    const float* dlr = dispL + (size_t)h * W;
    const float* drr = dispR + (size_t)h * W;

    const float2 dl2 = *(const float2*)(dlr + j0);
    const float2 dr2 = *(const float2*)(drr + j0);
    const float2 l0v = *(const float2*)(Lr + j0);
    const float2 l1v = *(const float2*)(Lr + HWsz + j0);
    const float2 l2v = *(const float2*)(Lr + 2*HWsz + j0);
    const float2 r0v = *(const float2*)(Rr + j0);
    const float2 r1v = *(const float2*)(Rr + HWsz + j0);
    const float2 r2v = *(const float2*)(Rr + 2*HWsz + j0);

    float sadL = 0.f, sadR = 0.f, lr1 = 0.f, lr2 = 0.f;
    float glo[2], gro[2], gelo[2], gero[2];

#pragma unroll
    for (int c = 0; c < 2; ++c) {
        const int j = j0 + c;
        const float dl = c ? dl2.y : dl2.x;
        const float dr = c ? dr2.y : dr2.x;
        const float xr = clampx((float)(j + 1) + dr);  // sample position into LEFT
        const float xl = clampx((float)(j + 1) - dl);  // sample position into RIGHT

        float er0 = sample_row(Lr,           xr);
        float er1 = sample_row(Lr + HWsz,    xr);
        float er2 = sample_row(Lr + 2*HWsz,  xr);
        float el0 = sample_row(Rr,           xl);
        float el1 = sample_row(Rr + HWsz,    xl);
        float el2 = sample_row(Rr + 2*HWsz,  xl);

        const float l0 = c ? l0v.y : l0v.x;
        const float l1 = c ? l1v.y : l1v.x;
        const float l2 = c ? l2v.y : l2v.x;
        const float r0 = c ? r0v.y : r0v.x;
        const float r1 = c ? r1v.y : r1v.x;
        const float r2 = c ? r2v.y : r2v.x;

        sadL += fabsf(l0-el0) + fabsf(l1-el1) + fabsf(l2-el2);
        sadR += fabsf(r0-er0) + fabsf(r1-er1) + fabsf(r2-er2);

        glo[c]  = (l0 + l1 + l2) * (1.0f/3.0f);
        gro[c]  = (r0 + r1 + r2) * (1.0f/3.0f);
        gelo[c] = (el0 + el1 + el2) * (1.0f/3.0f);
        gero[c] = (er0 + er1 + er2) * (1.0f/3.0f);

        float l2rv = sample_row(dlr, xr);
        float r2lv = sample_row(drr, xl);
        lr1 += fabsf(r2lv - dl);
        lr2 += fabsf(l2rv - dr);
    }

    const size_t p = (size_t)h * W + j0;
    *(float2*)(glm  + p) = make_float2(glo[0],  glo[1]);
    *(float2*)(grm  + p) = make_float2(gro[0],  gro[1]);
    *(float2*)(gelm + p) = make_float2(gelo[0], gelo[1]);
    *(float2*)(germ + p) = make_float2(gero[0], gero[1]);

    sadL = wred(sadL); sadR = wred(sadR); lr1 = wred(lr1); lr2 = wred(lr2);
    if ((tid & 63) == 0) {
        atomicAdd(&sb[0], sadL); atomicAdd(&sb[1], sadR);
        atomicAdd(&sb[2], lr1);  atomicAdd(&sb[3], lr2);
    }
    __syncthreads();
    const int b = blockIdx.y * gridDim.x + blockIdx.x;
    if (tid < 4) rp[tid * NBW + b] = sb[tid];
}

// ---------------------------------------------------------------------------
// Kernel B: ssim w=3 + disparity smoothness. V=4 cols/lane, vertical-sum-first
// register pipeline. One wave = one 8-row segment of a 248-col strip.
__global__ __launch_bounds__(256)
void s3_kernel(const float* __restrict__ glm, const float* __restrict__ gelm,
               const float* __restrict__ grm, const float* __restrict__ germ,
               const float* __restrict__ dispL, const float* __restrict__ dispR,
               float* __restrict__ s3p, float* __restrict__ smp) {
    __shared__ float sb[2];
    const int tid = threadIdx.x, wid = tid >> 6, lane = tid & 63;
    if (tid < 2) sb[tid] = 0.f;
    __syncthreads();

    const int z = blockIdx.z;
    const float* X = z ? grm  : glm;
    const float* Y = z ? germ : gelm;
    const float* D = z ? dispR : dispL;
    const int C0 = blockIdx.x * STRIDE;
    const int cb = C0 + 4 * lane;
    const int cba = min(cb, W - 4);
    const int o0 = (blockIdx.y * 4 + wid) * S3SEG;

    float xr_[3][4], yr_[3][4], dr_[3][4];
    float hxx[3][4], hyy[3][4], hxy[3][4];
    float m3x[2][4], m3y[2][4];
    float acc3 = 0.f, accS = 0.f;
    const float C1 = 1e-4f, C2 = 9e-4f;

    for (int n = 0; n < S3ROWS; ++n) {
        const int r = o0 + n;
        const int ra = min(r, H - 1);
        const float4 xv = *(const float4*)(X + (size_t)ra * W + cba);
        const float4 yv = *(const float4*)(Y + (size_t)ra * W + cba);
        const float4 dv = *(const float4*)(D + (size_t)ra * W + cba);
#pragma unroll
        for (int t = 0; t < 2; ++t)
#pragma unroll
            for (int k = 0; k < 4; ++k) {
                xr_[t][k] = xr_[t+1][k]; yr_[t][k] = yr_[t+1][k]; dr_[t][k] = dr_[t+1][k];
            }
        xr_[2][0] = xv.x; xr_[2][1] = xv.y; xr_[2][2] = xv.z; xr_[2][3] = xv.w;
        yr_[2][0] = yv.x; yr_[2][1] = yv.y; yr_[2][2] = yv.z; yr_[2][3] = yv.w;
        dr_[2][0] = dv.x; dr_[2][1] = dv.y; dr_[2][2] = dv.z; dr_[2][3] = dv.w;

        if (n >= 2) {
            float v3x[6], v3y[6], v3d[6];
#pragma unroll
            for (int k = 0; k < 4; ++k) {
                v3x[k] = xr_[0][k] + xr_[1][k] + xr_[2][k];
                v3y[k] = yr_[0][k] + yr_[1][k] + yr_[2][k];
                v3d[k] = dr_[0][k] + dr_[1][k] + dr_[2][k];
            }
            v3x[4] = __shfl_down(v3x[0],1,64); v3x[5] = __shfl_down(v3x[1],1,64);
            v3y[4] = __shfl_down(v3y[0],1,64); v3y[5] = __shfl_down(v3y[1],1,64);
            v3d[4] = __shfl_down(v3d[0],1,64); v3d[5] = __shfl_down(v3d[1],1,64);
            float xe = __shfl_down(xr_[1][0],1,64);
            float ye = __shfl_down(yr_[1][0],1,64);
            float de = __shfl_down(dr_[1][0],1,64);
            float xc[4] = {xr_[1][1], xr_[1][2], xr_[1][3], xe};   // x[r-1][cb+k+1]
            float yc[4] = {yr_[1][1], yr_[1][2], yr_[1][3], ye};
            float dc[4] = {dr_[1][1], dr_[1][2], dr_[1][3], de};

            float s3xv[4], mu3xv[4], mu3yv[4];
#pragma unroll
            for (int k = 0; k < 4; ++k) {
                s3xv[k] = v3x[k] + v3x[k+1] + v3x[k+2];
                mu3xv[k] = s3xv[k] * (1.f/9.f);
                mu3yv[k] = (v3y[k] + v3y[k+1] + v3y[k+2]) * (1.f/9.f);
            }
            float uxx[6], uyy[6], uxy[6];
#pragma unroll
            for (int k = 0; k < 4; ++k) {
                float tx = xc[k] - mu3xv[k], ty = yc[k] - mu3yv[k];
                uxx[k] = tx*tx; uyy[k] = ty*ty; uxy[k] = tx*ty;
            }
            uxx[4] = __shfl_down(uxx[0],1,64); uxx[5] = __shfl_down(uxx[1],1,64);
            uyy[4] = __shfl_down(uyy[0],1,64); uyy[5] = __shfl_down(uyy[1],1,64);
            uxy[4] = __shfl_down(uxy[0],1,64); uxy[5] = __shfl_down(uxy[1],1,64);
#pragma unroll
            for (int t = 0; t < 2; ++t)
#pragma unroll
                for (int k = 0; k < 4; ++k) {
                    hxx[t][k] = hxx[t+1][k]; hyy[t][k] = hyy[t+1][k]; hxy[t][k] = hxy[t+1][k];
                }
#pragma unroll
            for (int k = 0; k < 4; ++k) {
                hxx[2][k] = uxx[k] + uxx[k+1] + uxx[k+2];
                hyy[2][k] = uyy[k] + uyy[k+1] + uyy[k+2];
                hxy[2][k] = uxy[k] + uxy[k+1] + uxy[k+2];
                m3x[0][k] = m3x[1][k]; m3x[1][k] = mu3xv[k];
                m3y[0][k] = m3y[1][k]; m3y[1][k] = mu3yv[k];
            }
            const int i = r - 2;
            if ((n - 2) < S3SEG && i < H - 2) {
#pragma unroll
                for (int k = 0; k < 4; ++k) {
                    if (4*lane + k < STRIDE && cb + k <= W - 3) {
                        float lapd = (v3d[k] + v3d[k+1] + v3d[k+2]) - 9.f * dc[k];
                        float lapg = s3xv[k] - 9.f * xc[k];
                        accS += expf(-fabsf(lapg)) * fabsf(lapd);
                    }
                }
            }
        }
        if (n >= 4) {
            const int s = r - 4;
            if ((n - 4) < S3SEG && s < H - 4) {
                float cxe = __shfl_down(m3x[0][0],1,64);
                float cye = __shfl_down(m3y[0][0],1,64);
#pragma unroll
                for (int k = 0; k < 4; ++k) {
                    float cx = (k < 3) ? m3x[0][k+1] : cxe;   // mu3[s+1][t+1]
                    float cy = (k < 3) ? m3y[0][k+1] : cye;
                    float sxx = (hxx[0][k] + hxx[1][k] + hxx[2][k]) * (1.f/9.f);
                    float syy = (hyy[0][k] + hyy[1][k] + hyy[2][k]) * (1.f/9.f);
                    float sxy = (hxy[0][k] + hxy[1][k] + hxy[2][k]) * (1.f/9.f);
                    float nn = (2.f*cx*cy + C1) * (2.f*sxy + C2);
                    float dd = (cx*cx + cy*cy + C1) * (sxx + syy + C2);
                    float val = fminf(fmaxf(1.f - nn/dd, 0.f), 2.f);
                    if (4*lane + k < STRIDE && cb + k <= W - 5) acc3 += val;
                }
            }
        }
    }
    acc3 = wred(acc3); accS = wred(accS);
    if (lane == 0) { atomicAdd(&sb[0], acc3); atomicAdd(&sb[1], accS); }
    __syncthreads();
    const int b = blockIdx.y * NSTRIPS + blockIdx.x;
    if (tid == 0) { s3p[z*NB3 + b] = sb[0]; smp[z*NB3 + b] = sb[1]; }
}

// ---------------------------------------------------------------------------
// Kernel C: ssim w=5, same structure (halo 8 rows), SEG=8 for 2.25 waves/SIMD.
__global__ __launch_bounds__(256)
void s5_kernel(const float* __restrict__ glm, const float* __restrict__ gelm,
               const float* __restrict__ grm, const float* __restrict__ germ,
               float* __restrict__ s5p) {
    __shared__ float sb[1];
    const int tid = threadIdx.x, wid = tid >> 6, lane = tid & 63;
    if (tid == 0) sb[0] = 0.f;
    __syncthreads();

    const int z = blockIdx.z;
    const float* X = z ? grm  : glm;
    const float* Y = z ? germ : gelm;
    const int C0 = blockIdx.x * STRIDE;
    const int cb = C0 + 4 * lane;
    const int cba = min(cb, W - 4);
    const int o0 = (blockIdx.y * 4 + wid) * S5SEG;

    float xr_[5][4], yr_[5][4];
    float hxx[5][4], hyy[5][4], hxy[5][4];
    float m5x[3][4], m5y[3][4];
    float acc5 = 0.f;
    const float C1 = 1e-4f, C2 = 9e-4f;

    for (int n = 0; n < S5ROWS; ++n) {
        const int r = o0 + n;
        const int ra = min(r, H - 1);
        const float4 xv = *(const float4*)(X + (size_t)ra * W + cba);
        const float4 yv = *(const float4*)(Y + (size_t)ra * W + cba);
#pragma unroll
        for (int t = 0; t < 4; ++t)
#pragma unroll
            for (int k = 0; k < 4; ++k) { xr_[t][k] = xr_[t+1][k]; yr_[t][k] = yr_[t+1][k]; }
        xr_[4][0] = xv.x; xr_[4][1] = xv.y; xr_[4][2] = xv.z; xr_[4][3] = xv.w;
        yr_[4][0] = yv.x; yr_[4][1] = yv.y; yr_[4][2] = yv.z; yr_[4][3] = yv.w;

        if (n >= 4) {
            float v5x[8], v5y[8];
#pragma unroll
            for (int k = 0; k < 4; ++k) {
                v5x[k] = xr_[0][k] + xr_[1][k] + xr_[2][k] + xr_[3][k] + xr_[4][k];
                v5y[k] = yr_[0][k] + yr_[1][k] + yr_[2][k] + yr_[3][k] + yr_[4][k];
            }
#pragma unroll
            for (int k = 0; k < 4; ++k) {
                v5x[4+k] = __shfl_down(v5x[k],1,64);
                v5y[4+k] = __shfl_down(v5y[k],1,64);
            }
            float mu5xv[4], mu5yv[4];
#pragma unroll
            for (int k = 0; k < 4; ++k) {
                mu5xv[k] = (v5x[k]+v5x[k+1]+v5x[k+2]+v5x[k+3]+v5x[k+4]) * (1.f/25.f);
                mu5yv[k] = (v5y[k]+v5y[k+1]+v5y[k+2]+v5y[k+3]+v5y[k+4]) * (1.f/25.f);
            }
            float xe0 = __shfl_down(xr_[2][0],1,64), xe1 = __shfl_down(xr_[2][1],1,64);
            float ye0 = __shfl_down(yr_[2][0],1,64), ye1 = __shfl_down(yr_[2][1],1,64);
            float xc[4] = {xr_[2][2], xr_[2][3], xe0, xe1};   // x[p+2][t+2]
            float yc[4] = {yr_[2][2], yr_[2][3], ye0, ye1};
            float uxx[8], uyy[8], uxy[8];
#pragma unroll
            for (int k = 0; k < 4; ++k) {
                float tx = xc[k] - mu5xv[k], ty = yc[k] - mu5yv[k];
                uxx[k] = tx*tx; uyy[k] = ty*ty; uxy[k] = tx*ty;
            }
#pragma unroll
            for (int k = 0; k < 4; ++k) {
                uxx[4+k] = __shfl_down(uxx[k],1,64);
                uyy[4+k] = __shfl_down(uyy[k],1,64);
                uxy[4+k] = __shfl_down(uxy[k],1,64);
            }
#pragma unroll
            for (int t = 0; t < 4; ++t)
#pragma unroll
                for (int k = 0; k < 4; ++k) {
                    hxx[t][k] = hxx[t+1][k]; hyy[t][k] = hyy[t+1][k]; hxy[t][k] = hxy[t+1][k];
                }
#pragma unroll
            for (int k = 0; k < 4; ++k) {
                hxx[4][k] = uxx[k]+uxx[k+1]+uxx[k+2]+uxx[k+3]+uxx[k+4];
                hyy[4][k] = uyy[k]+uyy[k+1]+uyy[k+2]+uyy[k+3]+uyy[k+4];
                hxy[4][k] = uxy[k]+uxy[k+1]+uxy[k+2]+uxy[k+3]+uxy[k+4];
                m5x[0][k] = m5x[1][k]; m5x[1][k] = m5x[2][k]; m5x[2][k] = mu5xv[k];
                m5y[0][k] = m5y[1][k]; m5y[1][k] = m5y[2][k]; m5y[2][k] = mu5yv[k];
            }
        }
        if (n >= 8) {
            const int s = r - 8;
            if ((n - 8) < S5SEG && s < H - 8) {
                float ce0x = __shfl_down(m5x[0][0],1,64), ce1x = __shfl_down(m5x[0][1],1,64);
                float ce0y = __shfl_down(m5y[0][0],1,64), ce1y = __shfl_down(m5y[0][1],1,64);
#pragma unroll
                for (int k = 0; k < 4; ++k) {
                    float cx = (k < 2) ? m5x[0][k+2] : ((k == 2) ? ce0x : ce1x);  // mu5[s+2][t+2]
                    float cy = (k < 2) ? m5y[0][k+2] : ((k == 2) ? ce0y : ce1y);
                    float sxx = (hxx[0][k]+hxx[1][k]+hxx[2][k]+hxx[3][k]+hxx[4][k]) * (1.f/25.f);
                    float syy = (hyy[0][k]+hyy[1][k]+hyy[2][k]+hyy[3][k]+hyy[4][k]) * (1.f/25.f);
                    float sxy = (hxy[0][k]+hxy[1][k]+hxy[2][k]+hxy[3][k]+hxy[4][k]) * (1.f/25.f);
                    float nn = (2.f*cx*cy + C1) * (2.f*sxy + C2);
                    float dd = (cx*cx + cy*cy + C1) * (sxx + syy + C2);
                    float val = fminf(fmaxf(1.f - nn/dd, 0.f), 2.f);
                    if (4*lane + k < STRIDE && cb + k <= W - 9) acc5 += val;
                }
            }
        }
    }
    acc5 = wred(acc5);
    if (lane == 0) atomicAdd(&sb[0], acc5);
    __syncthreads();
    const int b = blockIdx.y * NSTRIPS + blockIdx.x;
    if (tid == 0) s5p[z*NB5 + b] = sb[0];
}

// ---------------------------------------------------------------------------
__global__ __launch_bounds__(1024)
void finalize_kernel(const float* __restrict__ rp, const float* __restrict__ s3p,
                     const float* __restrict__ smp, const float* __restrict__ s5p,
                     float* __restrict__ out) {
    __shared__ double sums[10];
    const int tid = threadIdx.x;
    if (tid < 10) sums[tid] = 0.0;
    __syncthreads();

    double a[10] = {0,0,0,0,0,0,0,0,0,0};
#pragma unroll
    for (int f = 0; f < 4; ++f)
        for (int i = tid; i < NBW; i += 1024) a[f] += (double)rp[f*NBW + i];
#pragma unroll
    for (int z = 0; z < 2; ++z) {
        for (int i = tid; i < NB3; i += 1024) a[4+z] += (double)s3p[z*NB3 + i];
        for (int i = tid; i < NB3; i += 1024) a[6+z] += (double)smp[z*NB3 + i];
        for (int i = tid; i < NB5; i += 1024) a[8+z] += (double)s5p[z*NB5 + i];
    }
#pragma unroll
    for (int f = 0; f < 10; ++f) {
        double v = a[f];
        for (int off = 32; off > 0; off >>= 1) v += __shfl_down(v, off, 64);
        if ((tid & 63) == 0) atomicAdd(&sums[f], v);
    }
    __syncthreads();
    if (tid == 0) {
        const double HW = (double)H * (double)W;
        double sadL = sums[0] / (3.0 * HW);
        double sadR = sums[1] / (3.0 * HW);
        double lr   = (sums[2] + sums[3]) / HW;
        const double c3  = (double)(H-4) * (double)(W-4);
        const double c5  = (double)(H-8) * (double)(W-8);
        const double csm = (double)(H-2) * (double)(W-2);
        double ssimL = 0.5 * sums[4] / c3 + 0.5 * sums[8] / c5;
        double ssimR = 0.5 * sums[5] / c3 + 0.5 * sums[9] / c5;
        double rec = 0.5 * ssimL + 0.5 * sadL + 0.5 * ssimR + 0.5 * sadR;
        double smooth = (sums[6] + sums[7]) / csm;
        out[0] = (float)rec;
        out[1] = (float)(0.1 * smooth);
        out[2] = (float)(0.1 * lr);
    }
}

// ---------------------------------------------------------------------------
extern "C" void kernel_launch(void* const* d_in, const int* in_sizes, int n_in,
                              void* d_out, int out_size, void* d_ws, size_t ws_size,
                              hipStream_t stream) {
    const float* dispL = (const float*)d_in[0];
    const float* dispR = (const float*)d_in[1];
    const float* left  = (const float*)d_in[2];
    const float* right = (const float*)d_in[3];
    float* out = (float*)d_out;

    float* rp  = (float*)d_ws;          // 4*4096
    float* s3p = rp  + 4*NBW;           // 2*288
    float* smp = s3p + 2*NB3;           // 2*288
    float* s5p = smp + 2*NB3;           // 2*288
    float* maps = s5p + 2*NB5;          // offset 72448 B, 16-aligned
    float* glm  = maps;
    float* grm  = maps + HWsz;
    float* gelm = maps + 2*HWsz;
    float* germ = maps + 3*HWsz;

    warp_kernel<<<dim3(4, 1024), 256, 0, stream>>>(dispL, dispR, left, right,
                                                   glm, grm, gelm, germ, rp);
    s3_kernel<<<dim3(NSTRIPS, S3BLKY, 2), 256, 0, stream>>>(glm, gelm, grm, germ,
                                                            dispL, dispR, s3p, smp);
    s5_kernel<<<dim3(NSTRIPS, S5BLKY, 2), 256, 0, stream>>>(glm, gelm, grm, germ, s5p);
    finalize_kernel<<<1, 1024, 0, stream>>>(rp, s3p, smp, s5p, out);
}